// Round 3
// baseline (583.549 us; speedup 1.0000x reference)
//
#include <hip/hip_runtime.h>

// KPConv fused v3 for MI355X (gfx950).
// v2 -> v3: ONE-LINE FIX. c-major K ordering (k2' = c*16 + k) spans 0..1023
// (pad rows k=15 scattered at k2'%16==15), so stage2's K loop must run 32
// iterations (1024), not v1's k-major 30 (960). v2 dropped cin 60..63 ->
// absmax 2.31. Everything else unchanged from v2.

typedef __attribute__((ext_vector_type(8))) short bf16x8;
typedef __attribute__((ext_vector_type(4))) float f32x4;
typedef __attribute__((ext_vector_type(4))) float floatx4;
typedef __attribute__((ext_vector_type(2))) unsigned u32x2;

#define NPTS        50000
#define PTS_PER_WG  16
#define KP_INV      (1.0f / 0.06f)

// pack two fp32 -> bf16x2 (round-half-up): 2x v_add_u32 + 1x v_perm_b32
static __device__ __forceinline__ unsigned pack2bf(float lo, float hi) {
    unsigned ul = __builtin_bit_cast(unsigned, lo) + 0x8000u;
    unsigned uh = __builtin_bit_cast(unsigned, hi) + 0x8000u;
    return __builtin_amdgcn_perm(uh, ul, 0x07060302u);
}

__global__ void kpconv_kernel(const float* __restrict__ q_pts,
                              const float* __restrict__ neighbors,
                              const float* __restrict__ x,
                              const float* __restrict__ kp,
                              const float* __restrict__ weights,
                              float* __restrict__ out) {
    // weighted, bf16, c-major K order k2' = c*16 + k, per point 1024 entries.
    // Dword-offset XOR-swizzled by (p&7)<<2 (bits 2-4) for bank spread.
    __shared__ __align__(16) unsigned short A2[PTS_PER_WG * 1024];

    const int tid  = threadIdx.x;
    const int wv   = tid >> 6;        // wave 0..3
    const int lane = tid & 63;
    const int quad = lane >> 4;       // 0..3
    const int r16  = lane & 15;
    const int wg   = blockIdx.x;

    // A-frag row k = r16 (k=15 is zero padding); clamp kp read in-bounds
    const int kr = (r16 < 15) ? r16 : 14;
    const float kx = kp[kr*3 + 0], ky = kp[kr*3 + 1], kz = kp[kr*3 + 2];

    // ===== stage 1: each wave: 4 points, weighted[c][k] -> A2 =====
    #pragma unroll 1
    for (int i = 0; i < 4; ++i) {
        const int  p = wv*4 + i;
        const long n = (long)wg * PTS_PER_WG + p;

        // neighbor coords for this lane's 8 m's (m = quad*8+j): 24 floats,
        // quad-uniform -> 6 broadcast float4 loads
        union { floatx4 v4[6]; float f[24]; } nb;
        const floatx4* nptr = (const floatx4*)(neighbors + n*96 + quad*24);
        #pragma unroll
        for (int q2 = 0; q2 < 6; ++q2) nb.v4[q2] = nptr[q2];
        const float qx = q_pts[n*3 + 0];
        const float qy = q_pts[n*3 + 1];
        const float qz = q_pts[n*3 + 2];

        // w[k=r16][m=quad*8+j] directly in A-frag layout
        union { bf16x8 v; unsigned u[4]; } af;
        #pragma unroll
        for (int jj = 0; jj < 4; ++jj) {
            float w2[2];
            #pragma unroll
            for (int h = 0; h < 2; ++h) {
                const int j = jj*2 + h;
                const float dx = nb.f[3*j + 0] - qx - kx;
                const float dy = nb.f[3*j + 1] - qy - ky;
                const float dz = nb.f[3*j + 2] - qz - kz;
                float w = 1.0f - sqrtf(dx*dx + dy*dy + dz*dz) * KP_INV;
                w = fmaxf(w, 0.0f);
                w2[h] = (r16 < 15) ? w : 0.0f;   // row 15 = zero pad
            }
            af.u[jj] = pack2bf(w2[0], w2[1]);
        }

        // 4 Cin tiles: B frag from global x (64B-coalesced strided dwords)
        const float* xp = x + n*2048 + quad*512;   // + j*64 + c
        const int sw = (p & 7) << 2;               // dword-unit swizzle
        #pragma unroll
        for (int t = 0; t < 4; ++t) {
            const int c = t*16 + r16;
            union { bf16x8 v; unsigned u[4]; } bf;
            #pragma unroll
            for (int jj = 0; jj < 4; ++jj)
                bf.u[jj] = pack2bf(xp[(jj*2)*64 + c], xp[(jj*2 + 1)*64 + c]);
            f32x4 acc = {0.f, 0.f, 0.f, 0.f};
            acc = __builtin_amdgcn_mfma_f32_16x16x32_bf16(af.v, bf.v, acc, 0, 0, 0);
            // D: col c = r16 (+tile), row k = quad*4+reg ->
            // A2[k2' = c*16 + quad*4 + reg], 4 adjacent bf16 = one b64
            const int Y = c*8 + quad*2;            // dword offset (even)
            u32x2 dd;
            dd.x = pack2bf(acc[0], acc[1]);
            dd.y = pack2bf(acc[2], acc[3]);
            *(u32x2*)&A2[p*1024 + ((Y ^ sw) << 1)] = dd;
        }
    }

    __syncthreads();   // the only barrier: A2 visible to all waves

    // ===== stage 2: out[16][64] = weighted(c-major) @ W' =====
    // wave wv owns Cout tile d = wv*16 + r16; K = 1024 (c-major), 32 iters.
    const int d     = wv*16 + r16;
    const int swr   = (r16 & 7) << 2;
    const int kb    = (quad*8) & 15;   // 0 or 8
    const int chalf = quad >> 1;       // c parity for this quad
    f32x4 oacc = {0.f, 0.f, 0.f, 0.f};
    for (int kk = 0; kk < 32; ++kk) {  // <-- v3 fix: 32 (1024 K), was 30
        // A frag: point row r16, 8 consecutive k2' (16B-aligned, swizzled)
        const int Y = kk*16 + quad*4;
        const bf16x8 a2 = *(const bf16x8*)&A2[r16*1024 + ((Y ^ swr) << 1)];
        // B frag: B[k2'][d] = W[k2'&15][k2'>>4][d]; k=15 pad -> dummy load
        const int c2 = kk*2 + chalf;
        const float* wp = weights + c2*64 + d;
        union { bf16x8 v; unsigned u[4]; } bw;
        #pragma unroll
        for (int jj = 0; jj < 4; ++jj) {
            const int k0 = kb + jj*2;
            int k1 = kb + jj*2 + 1;
            if (k1 == 15) k1 = 0;      // A-side zero; keep load in-bounds
            bw.u[jj] = pack2bf(wp[k0*4096], wp[k1*4096]);
        }
        oacc = __builtin_amdgcn_mfma_f32_16x16x32_bf16(a2, bw.v, oacc, 0, 0, 0);
    }

    // D: col d = r16 (+tile), row p = quad*4+reg
    #pragma unroll
    for (int reg = 0; reg < 4; ++reg) {
        const int p = quad*4 + reg;
        out[((long)wg * PTS_PER_WG + p)*64 + d] = oacc[reg];
    }
}

extern "C" void kernel_launch(void* const* d_in, const int* in_sizes, int n_in,
                              void* d_out, int out_size, void* d_ws, size_t ws_size,
                              hipStream_t stream) {
    // setup_inputs order: q_pts, s_pts, neighbors, neighb_inds, x, kernel_points, weights
    const float* q_pts     = (const float*)d_in[0];
    const float* neighbors = (const float*)d_in[2];
    const float* x         = (const float*)d_in[4];
    const float* kp        = (const float*)d_in[5];
    const float* weights   = (const float*)d_in[6];
    float* out = (float*)d_out;

    dim3 grid(NPTS / PTS_PER_WG);   // 3125, exact
    kpconv_kernel<<<grid, 256, 0, stream>>>(q_pts, neighbors, x, kp, weights, out);
}